// Round 2
// baseline (203.723 us; speedup 1.0000x reference)
//
#include <hip/hip_runtime.h>

#define B_ 2
#define C_ 256
#define S_ 2304
#define DH_ 64
#define O3_ 1536
#define INNER_ 512
#define LOGSMAX 4.605170185988092f

typedef __attribute__((ext_vector_type(8))) short short8;
typedef __attribute__((ext_vector_type(4))) float f32x4;
typedef __bf16 bf16x8 __attribute__((ext_vector_type(8)));

__device__ __forceinline__ unsigned short f2bf(float f) {
  unsigned u = __builtin_bit_cast(unsigned, f);
  u += 0x7FFFu + ((u >> 16) & 1u);
  return (unsigned short)(u >> 16);
}
__device__ __forceinline__ float bf2f(unsigned short h) {
  return __builtin_bit_cast(float, (unsigned)h << 16);
}
__device__ __forceinline__ bf16x8 as_bf(short8 v) {
  return __builtin_bit_cast(bf16x8, v);
}

// ---------------- K0a: fp32 -> bf16 bulk convert ----------------
__global__ __launch_bounds__(256) void k_conv_bf16(const float* __restrict__ src,
                                                   unsigned short* __restrict__ dst, int n) {
  int i = blockIdx.x * 256 + threadIdx.x;
  if (i < n) dst[i] = f2bf(src[i]);
}

// ---------------- K0b: transpose x [b][c][p] -> xT [b][p][c] (bf16) ----------------
__global__ __launch_bounds__(256) void k_transpose_x(const float* __restrict__ x,
                                                     unsigned short* __restrict__ xT) {
  __shared__ float tile[64][65];
  int p0 = blockIdx.x * 64, c0 = blockIdx.y * 64, b = blockIdx.z;
  int t = threadIdx.x;
  const float* xb = x + (size_t)b * C_ * S_;
#pragma unroll
  for (int i = 0; i < 16; i++) {
    int c = i * 4 + (t >> 6);
    int p = t & 63;
    tile[c][p] = xb[(size_t)(c0 + c) * S_ + p0 + p];
  }
  __syncthreads();
  unsigned short* xTb = xT + (size_t)b * S_ * C_;
#pragma unroll
  for (int i = 0; i < 16; i++) {
    int p = i * 4 + (t >> 6);
    int c = t & 63;
    xTb[(size_t)(p0 + p) * C_ + c0 + c] = f2bf(tile[c][p]);
  }
}

// ---------------- K1/K5: GEMM  C[b][m][n] = sum_k A[m][k] * BT[b][n][k] ----------------
// A: [M][K] bf16 (shared across batch), BT: [b][N][K] bf16, out fp32 or bf16.
// BK = 64 (two 32-deep MFMA steps per staged tile).
__global__ __launch_bounds__(256) void k_gemm(const unsigned short* __restrict__ A,
                                              const unsigned short* __restrict__ BT,
                                              void* __restrict__ outp,
                                              int M, int N, int K, int bf16out) {
  __shared__ __align__(16) unsigned short As[128][72];
  __shared__ __align__(16) unsigned short Bs[128][72];
  int t = threadIdx.x;
  int lane = t & 63, wv = t >> 6;
  int quad = lane >> 4, r15 = lane & 15;
  int wm = wv >> 1, wn = wv & 1;
  int m0 = blockIdx.y * 128, n0 = blockIdx.x * 128;
  int b = blockIdx.z;
  const unsigned short* BTb = BT + (size_t)b * N * K;

  f32x4 acc[4][4] = {};

  int srow = t >> 2;       // 0..63
  int sc = (t & 3) * 16;   // 0,16,32,48
  const unsigned short* ag = A + (size_t)(m0 + srow) * K + sc;
  const unsigned short* bg = BTb + (size_t)(n0 + srow) * K + sc;

  for (int k0 = 0; k0 < K; k0 += 64) {
    short8 a00 = *(const short8*)(ag + k0);
    short8 a01 = *(const short8*)(ag + k0 + 8);
    short8 a10 = *(const short8*)(ag + (size_t)64 * K + k0);
    short8 a11 = *(const short8*)(ag + (size_t)64 * K + k0 + 8);
    short8 b00 = *(const short8*)(bg + k0);
    short8 b01 = *(const short8*)(bg + k0 + 8);
    short8 b10 = *(const short8*)(bg + (size_t)64 * K + k0);
    short8 b11 = *(const short8*)(bg + (size_t)64 * K + k0 + 8);
    __syncthreads();
    *(short8*)&As[srow][sc] = a00;
    *(short8*)&As[srow][sc + 8] = a01;
    *(short8*)&As[srow + 64][sc] = a10;
    *(short8*)&As[srow + 64][sc + 8] = a11;
    *(short8*)&Bs[srow][sc] = b00;
    *(short8*)&Bs[srow][sc + 8] = b01;
    *(short8*)&Bs[srow + 64][sc] = b10;
    *(short8*)&Bs[srow + 64][sc + 8] = b11;
    __syncthreads();
#pragma unroll
    for (int ks = 0; ks < 2; ks++) {
      short8 af[4], bfr[4];
#pragma unroll
      for (int i = 0; i < 4; i++) af[i] = *(const short8*)&As[wm * 64 + i * 16 + r15][ks * 32 + quad * 8];
#pragma unroll
      for (int j = 0; j < 4; j++) bfr[j] = *(const short8*)&Bs[wn * 64 + j * 16 + r15][ks * 32 + quad * 8];
#pragma unroll
      for (int i = 0; i < 4; i++)
#pragma unroll
        for (int j = 0; j < 4; j++)
          acc[i][j] = __builtin_amdgcn_mfma_f32_16x16x32_bf16(as_bf(af[i]), as_bf(bfr[j]), acc[i][j], 0, 0, 0);
    }
  }
  if (bf16out) {
    unsigned short* Cb = (unsigned short*)outp + (size_t)b * M * N;
#pragma unroll
    for (int i = 0; i < 4; i++)
#pragma unroll
      for (int j = 0; j < 4; j++)
#pragma unroll
        for (int rr = 0; rr < 4; rr++) {
          int row = m0 + wm * 64 + i * 16 + quad * 4 + rr;
          int col = n0 + wn * 64 + j * 16 + r15;
          Cb[(size_t)row * N + col] = f2bf(acc[i][j][rr]);
        }
  } else {
    float* Cb = (float*)outp + (size_t)b * M * N;
#pragma unroll
    for (int i = 0; i < 4; i++)
#pragma unroll
      for (int j = 0; j < 4; j++)
#pragma unroll
        for (int rr = 0; rr < 4; rr++) {
          int row = m0 + wm * 64 + i * 16 + quad * 4 + rr;
          int col = n0 + wn * 64 + j * 16 + r15;
          Cb[(size_t)row * N + col] = acc[i][j][rr];
        }
  }
}

// ---------------- K2: bias + l2norm q,k (fold head scale into q), v -> vT ----------------
__global__ __launch_bounds__(256) void k_norm_qkv(const unsigned short* __restrict__ y,
                                                  const float* __restrict__ b_in,
                                                  const float* __restrict__ ss,
                                                  unsigned short* __restrict__ qn,
                                                  unsigned short* __restrict__ kn,
                                                  unsigned short* __restrict__ vT) {
  int t = threadIdx.x;
  int p = blockIdx.x * 256 + t;
  int bh = blockIdx.y;
  int b = bh >> 3, h = bh & 7;
  const unsigned short* yb = y + (size_t)b * O3_ * S_;
  float scale = __expf(fminf(ss[h], LOGSMAX));
#pragma unroll
  for (int qk = 0; qk < 2; qk++) {
    unsigned packed[32];
    float sumsq = 0.f;
    int obase = h * 192 + qk * 64;
#pragma unroll
    for (int d = 0; d < 64; d += 2) {
      float v0 = bf2f(yb[(size_t)(obase + d) * S_ + p]) + b_in[obase + d];
      float v1 = bf2f(yb[(size_t)(obase + d + 1) * S_ + p]) + b_in[obase + d + 1];
      sumsq += v0 * v0 + v1 * v1;
      packed[d >> 1] = (unsigned)f2bf(v0) | ((unsigned)f2bf(v1) << 16);
    }
    float inv = 1.f / fmaxf(sqrtf(sumsq), 1e-12f);
    if (qk == 0) inv *= scale;
    unsigned short* dst = (qk == 0 ? qn : kn) + ((size_t)bh * S_ + p) * 64;
    unsigned outw[32];
#pragma unroll
    for (int i = 0; i < 32; i++) {
      float v0 = bf2f((unsigned short)(packed[i] & 0xffffu)) * inv;
      float v1 = bf2f((unsigned short)(packed[i] >> 16)) * inv;
      outw[i] = (unsigned)f2bf(v0) | ((unsigned)f2bf(v1) << 16);
    }
    uint4* d4 = (uint4*)dst;
#pragma unroll
    for (int i = 0; i < 8; i++)
      d4[i] = make_uint4(outw[4 * i], outw[4 * i + 1], outw[4 * i + 2], outw[4 * i + 3]);
  }
  {
    int obase = h * 192 + 128;
#pragma unroll
    for (int d = 0; d < 64; d++) {
      float v = bf2f(yb[(size_t)(obase + d) * S_ + p]) + b_in[obase + d];
      vT[((size_t)bh * DH_ + d) * S_ + p] = f2bf(v);
    }
  }
}

// ---------------- K3: attention, 64-query tile per block, fixed-shift softmax ----------------
__global__ __launch_bounds__(256) void k_attn(const unsigned short* __restrict__ qn,
                                              const unsigned short* __restrict__ kn,
                                              const unsigned short* __restrict__ vT,
                                              const float* __restrict__ ss,
                                              float* __restrict__ outp) {
  __shared__ __align__(16) unsigned short Ks[64][72];
  __shared__ __align__(16) unsigned short Vs[64][72];   // V^T tile: [d][key]
  __shared__ __align__(16) unsigned short Ps[4][16][72];
  int t = threadIdx.x;
  int lane = t & 63, wv = t >> 6;
  int quad = lane >> 4, r15 = lane & 15;
  int bh = blockIdx.x;
  int q0 = blockIdx.y * 64;
  const unsigned short* qb = qn + (size_t)bh * S_ * DH_;
  const unsigned short* kb = kn + (size_t)bh * S_ * DH_;
  const unsigned short* vb = vT + (size_t)bh * DH_ * S_;
  float shift = __expf(fminf(ss[bh & 7], LOGSMAX));  // scale folded into q; |sim| <= shift

  int qrow = q0 + wv * 16 + r15;
  short8 qf0 = *(const short8*)(qb + (size_t)qrow * DH_ + quad * 8);
  short8 qf1 = *(const short8*)(qb + (size_t)qrow * DH_ + 32 + quad * 8);

  f32x4 Oacc[4] = {};
  float l_part[4] = {0.f, 0.f, 0.f, 0.f};

  int row = t >> 2;
  int c0 = (t & 3) * 8;
  for (int kt = 0; kt < 36; kt++) {
    short8 kv0 = *(const short8*)(kb + (size_t)(kt * 64 + row) * DH_ + c0);
    short8 kv1 = *(const short8*)(kb + (size_t)(kt * 64 + row) * DH_ + c0 + 32);
    short8 vv0 = *(const short8*)(vb + (size_t)row * S_ + kt * 64 + c0);
    short8 vv1 = *(const short8*)(vb + (size_t)row * S_ + kt * 64 + c0 + 32);
    __syncthreads();
    *(short8*)&Ks[row][c0] = kv0;
    *(short8*)&Ks[row][c0 + 32] = kv1;
    *(short8*)&Vs[row][c0] = vv0;
    *(short8*)&Vs[row][c0 + 32] = vv1;
    __syncthreads();
    // S = Q K^T  (m=query, n=key)
    f32x4 sc[4];
#pragma unroll
    for (int st = 0; st < 4; st++) {
      f32x4 a = {};
      short8 b0 = *(const short8*)&Ks[st * 16 + r15][quad * 8];
      a = __builtin_amdgcn_mfma_f32_16x16x32_bf16(as_bf(qf0), as_bf(b0), a, 0, 0, 0);
      short8 b1 = *(const short8*)&Ks[st * 16 + r15][32 + quad * 8];
      a = __builtin_amdgcn_mfma_f32_16x16x32_bf16(as_bf(qf1), as_bf(b1), a, 0, 0, 0);
      sc[st] = a;
    }
    // fixed-shift softmax numerator; P -> LDS in A-operand-ready layout
#pragma unroll
    for (int r = 0; r < 4; r++) {
      float e0 = __expf(sc[0][r] - shift);
      float e1 = __expf(sc[1][r] - shift);
      float e2 = __expf(sc[2][r] - shift);
      float e3 = __expf(sc[3][r] - shift);
      l_part[r] += e0 + e1 + e2 + e3;
      int prow = quad * 4 + r;
      Ps[wv][prow][r15] = f2bf(e0);
      Ps[wv][prow][16 + r15] = f2bf(e1);
      Ps[wv][prow][32 + r15] = f2bf(e2);
      Ps[wv][prow][48 + r15] = f2bf(e3);
    }
    __syncthreads();
    // O += P V
#pragma unroll
    for (int ks = 0; ks < 2; ks++) {
      short8 pa = *(const short8*)&Ps[wv][r15][ks * 32 + quad * 8];
#pragma unroll
      for (int j = 0; j < 4; j++) {
        short8 vb8 = *(const short8*)&Vs[j * 16 + r15][ks * 32 + quad * 8];
        Oacc[j] = __builtin_amdgcn_mfma_f32_16x16x32_bf16(as_bf(pa), as_bf(vb8), Oacc[j], 0, 0, 0);
      }
    }
  }
  float inv[4];
#pragma unroll
  for (int r = 0; r < 4; r++) {
    float l = l_part[r];
    l += __shfl_xor(l, 1);
    l += __shfl_xor(l, 2);
    l += __shfl_xor(l, 4);
    l += __shfl_xor(l, 8);
    inv[r] = 1.f / l;
  }
#pragma unroll
  for (int j = 0; j < 4; j++)
#pragma unroll
    for (int r = 0; r < 4; r++) {
      int orow = q0 + wv * 16 + quad * 4 + r;
      outp[((size_t)bh * S_ + orow) * DH_ + j * 16 + r15] = Oacc[j][r] * inv[r];
    }
}

// ---------------- K4: depthwise 3x3, attnout [bh][p][d] -> dwb [b][p][ch] bf16 ----------------
__global__ __launch_bounds__(256) void k_dwconv(const float* __restrict__ attno,
                                                const float* __restrict__ w_dw,
                                                unsigned short* __restrict__ dwb) {
  int t = threadIdx.x;
  int d = t & 63;
  int pj = t >> 6;
  int p = blockIdx.x * 4 + pj;
  int bh = blockIdx.y;
  int b = bh >> 3, h = bh & 7;
  int yy = p / 48, xx = p % 48;
  const float* src = attno + (size_t)bh * S_ * DH_ + d;
  int ch = h * 64 + d;
  float w[9];
#pragma unroll
  for (int i = 0; i < 9; i++) w[i] = w_dw[ch * 9 + i];
  float acc = 0.f;
#pragma unroll
  for (int dy = -1; dy <= 1; dy++) {
    int y2 = yy + dy;
    if (y2 < 0 || y2 >= 48) continue;
#pragma unroll
    for (int dx = -1; dx <= 1; dx++) {
      int x2 = xx + dx;
      if (x2 < 0 || x2 >= 48) continue;
      acc += src[(size_t)(y2 * 48 + x2) * DH_] * w[(dy + 1) * 3 + dx + 1];
    }
  }
  dwb[((size_t)b * S_ + p) * INNER_ + ch] = f2bf(acc);
}

// ---------------- K6: channel LN + scales/shifts + final ----------------
__global__ __launch_bounds__(256) void k_ln_final(const float* __restrict__ pw,
                                                  const float* __restrict__ gamma,
                                                  const float* __restrict__ beta,
                                                  const float* __restrict__ x,
                                                  float* __restrict__ out) {
  __shared__ float s_sum[16][17];
  __shared__ float s_ss[16][17];
  int t = threadIdx.x;
  int pl = t & 15, cq = t >> 4;
  int gid = blockIdx.x;
  int b = gid / (S_ / 16);
  int p = (gid % (S_ / 16)) * 16 + pl;
  const float* pwb = pw + (size_t)b * INNER_ * S_;
  float sum = 0.f, sq = 0.f;
#pragma unroll
  for (int j = 0; j < 32; j++) {
    float v = pwb[(size_t)(cq * 32 + j) * S_ + p];
    sum += v;
    sq += v * v;
  }
  s_sum[cq][pl] = sum;
  s_ss[cq][pl] = sq;
  __syncthreads();
  float tot = 0.f, tss = 0.f;
#pragma unroll
  for (int i = 0; i < 16; i++) {
    tot += s_sum[i][pl];
    tss += s_ss[i][pl];
  }
  float mu = tot * (1.f / 512.f);
  float var = tss * (1.f / 512.f) - mu * mu;
  float rsig = rsqrtf(var + 1e-5f);
  const float* xb = x + (size_t)b * C_ * S_;
  float* ob = out + (size_t)b * C_ * S_;
#pragma unroll
  for (int j = 0; j < 16; j++) {
    int cc = cq * 16 + j;
    float scv = (pwb[(size_t)cc * S_ + p] - mu) * rsig * gamma[cc] + beta[cc];
    float shv = (pwb[(size_t)(cc + 256) * S_ + p] - mu) * rsig * gamma[cc + 256] + beta[cc + 256];
    ob[(size_t)cc * S_ + p] = shv + xb[(size_t)cc * S_ + p] * scv;
  }
}

extern "C" void kernel_launch(void* const* d_in, const int* in_sizes, int n_in,
                              void* d_out, int out_size, void* d_ws, size_t ws_size,
                              hipStream_t stream) {
  const float* x = (const float*)d_in[0];
  const float* w_in = (const float*)d_in[1];
  const float* b_in = (const float*)d_in[2];
  const float* ss = (const float*)d_in[3];
  const float* w_dw = (const float*)d_in[4];
  const float* w_pw = (const float*)d_in[5];
  const float* gamma = (const float*)d_in[6];
  const float* beta = (const float*)d_in[7];
  float* out = (float*)d_out;
  char* ws = (char*)d_ws;

  unsigned short* xT = (unsigned short*)(ws + 0);          // 2,359,296
  unsigned short* w_inb = (unsigned short*)(ws + 2359296);  // 786,432
  unsigned short* w_pwb = (unsigned short*)(ws + 3145728);  // 524,288
  unsigned short* qn = (unsigned short*)(ws + 3670016);     // 4,718,592
  unsigned short* kn = (unsigned short*)(ws + 8388608);     // 4,718,592
  unsigned short* vT = (unsigned short*)(ws + 13107200);    // 4,718,592
  unsigned short* dwb = (unsigned short*)(ws + 17825792);   // 4,718,592
  char* big = ws + 22544384;                                // 18,874,368
  unsigned short* y = (unsigned short*)big;                 // bf16 [2][1536][2304]
  float* attno = (float*)big;                               // fp32 [16][2304][64] (y dead)
  float* pw = (float*)(big + 9437184);                      // fp32 [2][512][2304]

  k_conv_bf16<<<1536, 256, 0, stream>>>(w_in, w_inb, O3_ * C_);
  k_conv_bf16<<<1024, 256, 0, stream>>>(w_pw, w_pwb, INNER_ * INNER_);
  k_transpose_x<<<dim3(36, 4, 2), 256, 0, stream>>>(x, xT);
  k_gemm<<<dim3(18, 12, 2), 256, 0, stream>>>(w_inb, xT, y, O3_, S_, C_, 1);
  k_norm_qkv<<<dim3(9, 16), 256, 0, stream>>>(y, b_in, ss, qn, kn, vT);
  k_attn<<<dim3(16, 36), 256, 0, stream>>>(qn, kn, vT, ss, attno);
  k_dwconv<<<dim3(576, 16), 256, 0, stream>>>(attno, w_dw, dwb);
  k_gemm<<<dim3(18, 4, 2), 256, 0, stream>>>(w_pwb, dwb, pw, INNER_, S_, INNER_, 0);
  k_ln_final<<<288, 256, 0, stream>>>(pw, gamma, beta, x, out);
}

// Round 3
// 199.757 us; speedup vs baseline: 1.0199x; 1.0199x over previous
//
#include <hip/hip_runtime.h>

#define B_ 2
#define C_ 256
#define S_ 2304
#define DH_ 64
#define O3_ 1536
#define INNER_ 512
#define LOGSMAX 4.605170185988092f
#define LOG2E 1.4426950408889634f

typedef __attribute__((ext_vector_type(8))) short short8;
typedef __attribute__((ext_vector_type(4))) float f32x4;
typedef __attribute__((ext_vector_type(16))) float f32x16;
typedef __attribute__((ext_vector_type(4))) unsigned short us4;
typedef __bf16 bf16x8 __attribute__((ext_vector_type(8)));

__device__ __forceinline__ unsigned short f2bf(float f) {
  unsigned u = __builtin_bit_cast(unsigned, f);
  u += 0x7FFFu + ((u >> 16) & 1u);
  return (unsigned short)(u >> 16);
}
__device__ __forceinline__ float bf2f(unsigned short h) {
  return __builtin_bit_cast(float, (unsigned)h << 16);
}
__device__ __forceinline__ bf16x8 as_bf(short8 v) {
  return __builtin_bit_cast(bf16x8, v);
}
__device__ __forceinline__ float fexp2(float x) {
#if __has_builtin(__builtin_amdgcn_exp2f)
  return __builtin_amdgcn_exp2f(x);
#else
  return __expf(x * 0.6931471805599453f);
#endif
}

// ---------------- K0: fused prep: x transpose + both weight converts ----------------
__global__ __launch_bounds__(256) void k_prep(const float* __restrict__ x,
                                              const float* __restrict__ w_in,
                                              const float* __restrict__ w_pw,
                                              unsigned short* __restrict__ xT,
                                              unsigned short* __restrict__ w_inb,
                                              unsigned short* __restrict__ w_pwb) {
  __shared__ float tile[64][65];
  int blk = blockIdx.x;
  int t = threadIdx.x;
  if (blk < 288) {  // transpose x [b][c][p] -> xT [b][p][c] bf16
    int p0 = (blk % 36) * 64, c0 = ((blk / 36) % 4) * 64, b = blk / 144;
    const float* xb = x + (size_t)b * C_ * S_;
#pragma unroll
    for (int i = 0; i < 16; i++) {
      int c = i * 4 + (t >> 6);
      int p = t & 63;
      tile[c][p] = xb[(size_t)(c0 + c) * S_ + p0 + p];
    }
    __syncthreads();
    unsigned short* xTb = xT + (size_t)b * S_ * C_;
#pragma unroll
    for (int i = 0; i < 16; i++) {
      int p = i * 4 + (t >> 6);
      int c = t & 63;
      xTb[(size_t)(p0 + p) * C_ + c0 + c] = f2bf(tile[c][p]);
    }
  } else if (blk < 288 + 1536) {
    int i = (blk - 288) * 256 + t;
    w_inb[i] = f2bf(w_in[i]);
  } else {
    int i = (blk - 1824) * 256 + t;
    w_pwb[i] = f2bf(w_pw[i]);
  }
}

// ---------------- K1/K5: GEMM  C[b][m][n] = sum_k A[m][k] * BT[b][n][k] ----------------
__global__ __launch_bounds__(256) void k_gemm(const unsigned short* __restrict__ A,
                                              const unsigned short* __restrict__ BT,
                                              void* __restrict__ outp,
                                              int M, int N, int K, int bf16out) {
  __shared__ __align__(16) unsigned short As[128][72];
  __shared__ __align__(16) unsigned short Bs[128][72];
  int t = threadIdx.x;
  int lane = t & 63, wv = t >> 6;
  int quad = lane >> 4, r15 = lane & 15;
  int wm = wv >> 1, wn = wv & 1;
  int m0 = blockIdx.y * 128, n0 = blockIdx.x * 128;
  int b = blockIdx.z;
  const unsigned short* BTb = BT + (size_t)b * N * K;

  f32x4 acc[4][4] = {};

  int srow = t >> 2;
  int sc = (t & 3) * 16;
  const unsigned short* ag = A + (size_t)(m0 + srow) * K + sc;
  const unsigned short* bg = BTb + (size_t)(n0 + srow) * K + sc;

  for (int k0 = 0; k0 < K; k0 += 64) {
    short8 a00 = *(const short8*)(ag + k0);
    short8 a01 = *(const short8*)(ag + k0 + 8);
    short8 a10 = *(const short8*)(ag + (size_t)64 * K + k0);
    short8 a11 = *(const short8*)(ag + (size_t)64 * K + k0 + 8);
    short8 b00 = *(const short8*)(bg + k0);
    short8 b01 = *(const short8*)(bg + k0 + 8);
    short8 b10 = *(const short8*)(bg + (size_t)64 * K + k0);
    short8 b11 = *(const short8*)(bg + (size_t)64 * K + k0 + 8);
    __syncthreads();
    *(short8*)&As[srow][sc] = a00;
    *(short8*)&As[srow][sc + 8] = a01;
    *(short8*)&As[srow + 64][sc] = a10;
    *(short8*)&As[srow + 64][sc + 8] = a11;
    *(short8*)&Bs[srow][sc] = b00;
    *(short8*)&Bs[srow][sc + 8] = b01;
    *(short8*)&Bs[srow + 64][sc] = b10;
    *(short8*)&Bs[srow + 64][sc + 8] = b11;
    __syncthreads();
#pragma unroll
    for (int ks = 0; ks < 2; ks++) {
      short8 af[4], bfr[4];
#pragma unroll
      for (int i = 0; i < 4; i++) af[i] = *(const short8*)&As[wm * 64 + i * 16 + r15][ks * 32 + quad * 8];
#pragma unroll
      for (int j = 0; j < 4; j++) bfr[j] = *(const short8*)&Bs[wn * 64 + j * 16 + r15][ks * 32 + quad * 8];
#pragma unroll
      for (int i = 0; i < 4; i++)
#pragma unroll
        for (int j = 0; j < 4; j++)
          acc[i][j] = __builtin_amdgcn_mfma_f32_16x16x32_bf16(as_bf(af[i]), as_bf(bfr[j]), acc[i][j], 0, 0, 0);
    }
  }
  if (bf16out) {
    unsigned short* Cb = (unsigned short*)outp + (size_t)b * M * N;
#pragma unroll
    for (int i = 0; i < 4; i++)
#pragma unroll
      for (int j = 0; j < 4; j++)
#pragma unroll
        for (int rr = 0; rr < 4; rr++) {
          int row = m0 + wm * 64 + i * 16 + quad * 4 + rr;
          int col = n0 + wn * 64 + j * 16 + r15;
          Cb[(size_t)row * N + col] = f2bf(acc[i][j][rr]);
        }
  } else {
    float* Cb = (float*)outp + (size_t)b * M * N;
#pragma unroll
    for (int i = 0; i < 4; i++)
#pragma unroll
      for (int j = 0; j < 4; j++)
#pragma unroll
        for (int rr = 0; rr < 4; rr++) {
          int row = m0 + wm * 64 + i * 16 + quad * 4 + rr;
          int col = n0 + wn * 64 + j * 16 + r15;
          Cb[(size_t)row * N + col] = acc[i][j][rr];
        }
  }
}

// ---------------- K2: bias + l2norm q,k (fold head scale * log2e into q), v -> vT ----------------
__global__ __launch_bounds__(256) void k_norm_qkv(const unsigned short* __restrict__ y,
                                                  const float* __restrict__ b_in,
                                                  const float* __restrict__ ss,
                                                  unsigned short* __restrict__ qn,
                                                  unsigned short* __restrict__ kn,
                                                  unsigned short* __restrict__ vT) {
  int t = threadIdx.x;
  int p = blockIdx.x * 256 + t;
  int bh = blockIdx.y;
  int b = bh >> 3, h = bh & 7;
  const unsigned short* yb = y + (size_t)b * O3_ * S_;
  float scale = __expf(fminf(ss[h], LOGSMAX)) * LOG2E;  // fold log2e for exp2 softmax
#pragma unroll
  for (int qk = 0; qk < 2; qk++) {
    unsigned packed[32];
    float sumsq = 0.f;
    int obase = h * 192 + qk * 64;
#pragma unroll
    for (int d = 0; d < 64; d += 2) {
      float v0 = bf2f(yb[(size_t)(obase + d) * S_ + p]) + b_in[obase + d];
      float v1 = bf2f(yb[(size_t)(obase + d + 1) * S_ + p]) + b_in[obase + d + 1];
      sumsq += v0 * v0 + v1 * v1;
      packed[d >> 1] = (unsigned)f2bf(v0) | ((unsigned)f2bf(v1) << 16);
    }
    float inv = 1.f / fmaxf(sqrtf(sumsq), 1e-12f);
    if (qk == 0) inv *= scale;
    unsigned short* dst = (qk == 0 ? qn : kn) + ((size_t)bh * S_ + p) * 64;
    unsigned outw[32];
#pragma unroll
    for (int i = 0; i < 32; i++) {
      float v0 = bf2f((unsigned short)(packed[i] & 0xffffu)) * inv;
      float v1 = bf2f((unsigned short)(packed[i] >> 16)) * inv;
      outw[i] = (unsigned)f2bf(v0) | ((unsigned)f2bf(v1) << 16);
    }
    uint4* d4 = (uint4*)dst;
#pragma unroll
    for (int i = 0; i < 8; i++)
      d4[i] = make_uint4(outw[4 * i], outw[4 * i + 1], outw[4 * i + 2], outw[4 * i + 3]);
  }
  {
    int obase = h * 192 + 128;
#pragma unroll
    for (int d = 0; d < 64; d++) {
      float v = bf2f(yb[(size_t)(obase + d) * S_ + p]) + b_in[obase + d];
      vT[((size_t)bh * DH_ + d) * S_ + p] = f2bf(v);
    }
  }
}

// ---------------- K3: attention, 32x32 MFMA, transposed-S, 2 waves x 32 queries ----------------
// S^T = K Q^T (m=key, n=query); O^T = V^T P^T (m=d, n=query). Fixed-shift softmax.
__global__ __launch_bounds__(128) void k_attn(const unsigned short* __restrict__ qn,
                                              const unsigned short* __restrict__ kn,
                                              const unsigned short* __restrict__ vT,
                                              const float* __restrict__ ss,
                                              float* __restrict__ outp) {
  __shared__ __align__(16) unsigned short Ks[64][72];      // [key][d]
  __shared__ __align__(16) unsigned short Vs[64][72];      // [d][key]
  __shared__ __align__(16) unsigned short Ps[2][32][72];   // per wave [q][key]
  int t = threadIdx.x;
  int w = t >> 6;
  int lane = t & 63;
  int l31 = lane & 31, hi = lane >> 5;
  int bh = blockIdx.x;
  int q0 = blockIdx.y * 64 + w * 32;
  const unsigned short* qb = qn + (size_t)bh * S_ * DH_;
  const unsigned short* kb = kn + (size_t)bh * S_ * DH_;
  const unsigned short* vb = vT + (size_t)bh * DH_ * S_;
  float shift2 = __expf(fminf(ss[bh & 7], LOGSMAX)) * LOG2E;  // |s'| <= shift2

  // Q as B-fragment: n=query=l31, k(d) = ks*16 + hi*8 + j
  const unsigned short* qrow = qb + (size_t)(q0 + l31) * DH_ + hi * 8;
  short8 qf[4];
#pragma unroll
  for (int ks = 0; ks < 4; ks++) qf[ks] = *(const short8*)(qrow + ks * 16);

  const f32x16 z16 = {};
  f32x16 O0 = z16, O1 = z16;
  float l_part = 0.f;

  int row = t >> 1;          // 0..63
  int c0 = (t & 1) * 32;     // 0 or 32
  const unsigned short* kg = kb + (size_t)row * DH_ + c0;
  const unsigned short* vg = vb + (size_t)row * S_ + c0;

  for (int kt = 0; kt < 36; kt++) {
    short8 k0 = *(const short8*)(kg + (size_t)kt * 64 * DH_);
    short8 k1 = *(const short8*)(kg + (size_t)kt * 64 * DH_ + 8);
    short8 k2 = *(const short8*)(kg + (size_t)kt * 64 * DH_ + 16);
    short8 k3 = *(const short8*)(kg + (size_t)kt * 64 * DH_ + 24);
    short8 v0 = *(const short8*)(vg + kt * 64);
    short8 v1 = *(const short8*)(vg + kt * 64 + 8);
    short8 v2 = *(const short8*)(vg + kt * 64 + 16);
    short8 v3 = *(const short8*)(vg + kt * 64 + 24);
    __syncthreads();
    *(short8*)&Ks[row][c0] = k0;
    *(short8*)&Ks[row][c0 + 8] = k1;
    *(short8*)&Ks[row][c0 + 16] = k2;
    *(short8*)&Ks[row][c0 + 24] = k3;
    *(short8*)&Vs[row][c0] = v0;
    *(short8*)&Vs[row][c0 + 8] = v1;
    *(short8*)&Vs[row][c0 + 16] = v2;
    *(short8*)&Vs[row][c0 + 24] = v3;
    __syncthreads();
    // S^T = K Q^T : A = K-tile (m=key), B = Q regs (n=query)
    f32x16 sc0, sc1;
    {
      short8 a0 = *(const short8*)&Ks[l31][hi * 8];
      short8 a1 = *(const short8*)&Ks[32 + l31][hi * 8];
      sc0 = __builtin_amdgcn_mfma_f32_32x32x16_bf16(as_bf(a0), as_bf(qf[0]), z16, 0, 0, 0);
      sc1 = __builtin_amdgcn_mfma_f32_32x32x16_bf16(as_bf(a1), as_bf(qf[0]), z16, 0, 0, 0);
    }
#pragma unroll
    for (int ks = 1; ks < 4; ks++) {
      short8 a0 = *(const short8*)&Ks[l31][ks * 16 + hi * 8];
      short8 a1 = *(const short8*)&Ks[32 + l31][ks * 16 + hi * 8];
      sc0 = __builtin_amdgcn_mfma_f32_32x32x16_bf16(as_bf(a0), as_bf(qf[ks]), sc0, 0, 0, 0);
      sc1 = __builtin_amdgcn_mfma_f32_32x32x16_bf16(as_bf(a1), as_bf(qf[ks]), sc1, 0, 0, 0);
    }
    // exp2 numerator; P^T -> LDS as [q][key], 4 consecutive keys per b64 write
    float lsum = 0.f;
#pragma unroll
    for (int mt = 0; mt < 2; mt++) {
      const f32x16& s = mt ? sc1 : sc0;
#pragma unroll
      for (int g = 0; g < 4; g++) {
        float e0 = fexp2(s[g * 4 + 0] - shift2);
        float e1 = fexp2(s[g * 4 + 1] - shift2);
        float e2 = fexp2(s[g * 4 + 2] - shift2);
        float e3 = fexp2(s[g * 4 + 3] - shift2);
        lsum += (e0 + e1) + (e2 + e3);
        us4 pk = {f2bf(e0), f2bf(e1), f2bf(e2), f2bf(e3)};
        *(us4*)&Ps[w][l31][mt * 32 + g * 8 + hi * 4] = pk;
      }
    }
    l_part += lsum;
    // O^T += V^T P^T : A = V-tile (m=d), B = P (n=query) — Ps is same-wave, no barrier
#pragma unroll
    for (int ks = 0; ks < 4; ks++) {
      short8 pb = *(const short8*)&Ps[w][l31][ks * 16 + hi * 8];
      short8 va0 = *(const short8*)&Vs[l31][ks * 16 + hi * 8];
      short8 va1 = *(const short8*)&Vs[32 + l31][ks * 16 + hi * 8];
      O0 = __builtin_amdgcn_mfma_f32_32x32x16_bf16(as_bf(va0), as_bf(pb), O0, 0, 0, 0);
      O1 = __builtin_amdgcn_mfma_f32_32x32x16_bf16(as_bf(va1), as_bf(pb), O1, 0, 0, 0);
    }
  }
  float l = l_part + __shfl_xor(l_part, 32);
  float inv = 1.f / l;
  float* orow = outp + ((size_t)bh * S_ + q0 + l31) * DH_;
#pragma unroll
  for (int mt = 0; mt < 2; mt++) {
    const f32x16& O = mt ? O1 : O0;
#pragma unroll
    for (int g = 0; g < 4; g++) {
      f32x4 o4 = {O[g * 4 + 0] * inv, O[g * 4 + 1] * inv, O[g * 4 + 2] * inv, O[g * 4 + 3] * inv};
      *(f32x4*)&orow[mt * 32 + g * 8 + hi * 4] = o4;
    }
  }
}

// ---------------- K4: depthwise 3x3, attnout [bh][p][d] -> dwb [b][p][ch] bf16 ----------------
__global__ __launch_bounds__(256) void k_dwconv(const float* __restrict__ attno,
                                                const float* __restrict__ w_dw,
                                                unsigned short* __restrict__ dwb) {
  int t = threadIdx.x;
  int d = t & 63;
  int pj = t >> 6;
  int p = blockIdx.x * 4 + pj;
  int bh = blockIdx.y;
  int b = bh >> 3, h = bh & 7;
  int yy = p / 48, xx = p % 48;
  const float* src = attno + (size_t)bh * S_ * DH_ + d;
  int ch = h * 64 + d;
  float w[9];
#pragma unroll
  for (int i = 0; i < 9; i++) w[i] = w_dw[ch * 9 + i];
  float acc = 0.f;
#pragma unroll
  for (int dy = -1; dy <= 1; dy++) {
    int y2 = yy + dy;
    if (y2 < 0 || y2 >= 48) continue;
#pragma unroll
    for (int dx = -1; dx <= 1; dx++) {
      int x2 = xx + dx;
      if (x2 < 0 || x2 >= 48) continue;
      acc += src[(size_t)(y2 * 48 + x2) * DH_] * w[(dy + 1) * 3 + dx + 1];
    }
  }
  dwb[((size_t)b * S_ + p) * INNER_ + ch] = f2bf(acc);
}

// ---------------- K6: channel LN + scales/shifts + final ----------------
__global__ __launch_bounds__(256) void k_ln_final(const float* __restrict__ pw,
                                                  const float* __restrict__ gamma,
                                                  const float* __restrict__ beta,
                                                  const float* __restrict__ x,
                                                  float* __restrict__ out) {
  __shared__ float s_sum[16][17];
  __shared__ float s_ss[16][17];
  int t = threadIdx.x;
  int pl = t & 15, cq = t >> 4;
  int gid = blockIdx.x;
  int b = gid / (S_ / 16);
  int p = (gid % (S_ / 16)) * 16 + pl;
  const float* pwb = pw + (size_t)b * INNER_ * S_;
  float sum = 0.f, sq = 0.f;
#pragma unroll
  for (int j = 0; j < 32; j++) {
    float v = pwb[(size_t)(cq * 32 + j) * S_ + p];
    sum += v;
    sq += v * v;
  }
  s_sum[cq][pl] = sum;
  s_ss[cq][pl] = sq;
  __syncthreads();
  float tot = 0.f, tss = 0.f;
#pragma unroll
  for (int i = 0; i < 16; i++) {
    tot += s_sum[i][pl];
    tss += s_ss[i][pl];
  }
  float mu = tot * (1.f / 512.f);
  float var = tss * (1.f / 512.f) - mu * mu;
  float rsig = rsqrtf(var + 1e-5f);
  const float* xb = x + (size_t)b * C_ * S_;
  float* ob = out + (size_t)b * C_ * S_;
#pragma unroll
  for (int j = 0; j < 16; j++) {
    int cc = cq * 16 + j;
    float scv = (pwb[(size_t)cc * S_ + p] - mu) * rsig * gamma[cc] + beta[cc];
    float shv = (pwb[(size_t)(cc + 256) * S_ + p] - mu) * rsig * gamma[cc + 256] + beta[cc + 256];
    ob[(size_t)cc * S_ + p] = shv + xb[(size_t)cc * S_ + p] * scv;
  }
}

extern "C" void kernel_launch(void* const* d_in, const int* in_sizes, int n_in,
                              void* d_out, int out_size, void* d_ws, size_t ws_size,
                              hipStream_t stream) {
  const float* x = (const float*)d_in[0];
  const float* w_in = (const float*)d_in[1];
  const float* b_in = (const float*)d_in[2];
  const float* ss = (const float*)d_in[3];
  const float* w_dw = (const float*)d_in[4];
  const float* w_pw = (const float*)d_in[5];
  const float* gamma = (const float*)d_in[6];
  const float* beta = (const float*)d_in[7];
  float* out = (float*)d_out;
  char* ws = (char*)d_ws;

  unsigned short* xT = (unsigned short*)(ws + 0);           // 2,359,296
  unsigned short* w_inb = (unsigned short*)(ws + 2359296);  // 786,432
  unsigned short* w_pwb = (unsigned short*)(ws + 3145728);  // 524,288
  unsigned short* qn = (unsigned short*)(ws + 3670016);     // 4,718,592
  unsigned short* kn = (unsigned short*)(ws + 8388608);     // 4,718,592
  unsigned short* vT = (unsigned short*)(ws + 13107200);    // 4,718,592
  unsigned short* dwb = (unsigned short*)(ws + 17825792);   // 4,718,592
  char* big = ws + 22544384;                                // 18,874,368
  unsigned short* y = (unsigned short*)big;                 // bf16 [2][1536][2304]
  float* attno = (float*)big;                               // fp32 [16][2304][64] (y dead)
  float* pw = (float*)(big + 9437184);                      // fp32 [2][512][2304]

  k_prep<<<2848, 256, 0, stream>>>(x, w_in, w_pw, xT, w_inb, w_pwb);
  k_gemm<<<dim3(18, 12, 2), 256, 0, stream>>>(w_inb, xT, y, O3_, S_, C_, 1);
  k_norm_qkv<<<dim3(9, 16), 256, 0, stream>>>(y, b_in, ss, qn, kn, vT);
  k_attn<<<dim3(16, 36), 128, 0, stream>>>(qn, kn, vT, ss, attno);
  k_dwconv<<<dim3(576, 16), 256, 0, stream>>>(attno, w_dw, dwb);
  k_gemm<<<dim3(18, 4, 2), 256, 0, stream>>>(w_pwb, dwb, pw, INNER_, S_, INNER_, 0);
  k_ln_final<<<288, 256, 0, stream>>>(pw, gamma, beta, x, out);
}

// Round 4
// 180.922 us; speedup vs baseline: 1.1260x; 1.1041x over previous
//
#include <hip/hip_runtime.h>

#define B_ 2
#define C_ 256
#define S_ 2304
#define DH_ 64
#define O3_ 1536
#define INNER_ 512
#define LOGSMAX 4.605170185988092f
#define LOG2E 1.4426950408889634f

typedef __attribute__((ext_vector_type(8))) short short8;
typedef __attribute__((ext_vector_type(4))) float f32x4;
typedef __attribute__((ext_vector_type(16))) float f32x16;
typedef __attribute__((ext_vector_type(4))) unsigned short us4;
typedef __bf16 bf16x8 __attribute__((ext_vector_type(8)));

__device__ __forceinline__ unsigned short f2bf(float f) {
  unsigned u = __builtin_bit_cast(unsigned, f);
  u += 0x7FFFu + ((u >> 16) & 1u);
  return (unsigned short)(u >> 16);
}
__device__ __forceinline__ float bf2f(unsigned short h) {
  return __builtin_bit_cast(float, (unsigned)h << 16);
}
__device__ __forceinline__ bf16x8 as_bf(short8 v) {
  return __builtin_bit_cast(bf16x8, v);
}
__device__ __forceinline__ float fexp2(float x) {
#if __has_builtin(__builtin_amdgcn_exp2f)
  return __builtin_amdgcn_exp2f(x);
#else
  return __expf(x * 0.6931471805599453f);
#endif
}
__device__ __forceinline__ float frcp(float x) {
#if __has_builtin(__builtin_amdgcn_rcpf)
  return __builtin_amdgcn_rcpf(x);
#else
  return 1.f / x;
#endif
}

// ---------------- K0: fused prep: x transpose + both weight converts ----------------
__global__ __launch_bounds__(256) void k_prep(const float* __restrict__ x,
                                              const float* __restrict__ w_in,
                                              const float* __restrict__ w_pw,
                                              unsigned short* __restrict__ xT,
                                              unsigned short* __restrict__ w_inb,
                                              unsigned short* __restrict__ w_pwb) {
  __shared__ float tile[64][65];
  int blk = blockIdx.x;
  int t = threadIdx.x;
  if (blk < 288) {  // transpose x [b][c][p] -> xT [b][p][c] bf16
    int p0 = (blk % 36) * 64, c0 = ((blk / 36) % 4) * 64, b = blk / 144;
    const float* xb = x + (size_t)b * C_ * S_;
#pragma unroll
    for (int i = 0; i < 16; i++) {
      int c = i * 4 + (t >> 6);
      int p = t & 63;
      tile[c][p] = xb[(size_t)(c0 + c) * S_ + p0 + p];
    }
    __syncthreads();
    unsigned short* xTb = xT + (size_t)b * S_ * C_;
#pragma unroll
    for (int i = 0; i < 16; i++) {
      int p = i * 4 + (t >> 6);
      int c = t & 63;
      xTb[(size_t)(p0 + p) * C_ + c0 + c] = f2bf(tile[c][p]);
    }
  } else if (blk < 288 + 1536) {
    int i = (blk - 288) * 256 + t;
    w_inb[i] = f2bf(w_in[i]);
  } else {
    int i = (blk - 1824) * 256 + t;
    w_pwb[i] = f2bf(w_pw[i]);
  }
}

// ---------------- K1/K5: GEMM  C[b][m][n] = sum_k A[m][k] * BT[b][n][k] ----------------
__global__ __launch_bounds__(256) void k_gemm(const unsigned short* __restrict__ A,
                                              const unsigned short* __restrict__ BT,
                                              void* __restrict__ outp,
                                              int M, int N, int K, int bf16out) {
  __shared__ __align__(16) unsigned short As[128][72];
  __shared__ __align__(16) unsigned short Bs[128][72];
  int t = threadIdx.x;
  int lane = t & 63, wv = t >> 6;
  int quad = lane >> 4, r15 = lane & 15;
  int wm = wv >> 1, wn = wv & 1;
  int m0 = blockIdx.y * 128, n0 = blockIdx.x * 128;
  int b = blockIdx.z;
  const unsigned short* BTb = BT + (size_t)b * N * K;

  f32x4 acc[4][4] = {};

  int srow = t >> 2;
  int sc = (t & 3) * 16;
  const unsigned short* ag = A + (size_t)(m0 + srow) * K + sc;
  const unsigned short* bg = BTb + (size_t)(n0 + srow) * K + sc;

  for (int k0 = 0; k0 < K; k0 += 64) {
    short8 a00 = *(const short8*)(ag + k0);
    short8 a01 = *(const short8*)(ag + k0 + 8);
    short8 a10 = *(const short8*)(ag + (size_t)64 * K + k0);
    short8 a11 = *(const short8*)(ag + (size_t)64 * K + k0 + 8);
    short8 b00 = *(const short8*)(bg + k0);
    short8 b01 = *(const short8*)(bg + k0 + 8);
    short8 b10 = *(const short8*)(bg + (size_t)64 * K + k0);
    short8 b11 = *(const short8*)(bg + (size_t)64 * K + k0 + 8);
    __syncthreads();
    *(short8*)&As[srow][sc] = a00;
    *(short8*)&As[srow][sc + 8] = a01;
    *(short8*)&As[srow + 64][sc] = a10;
    *(short8*)&As[srow + 64][sc + 8] = a11;
    *(short8*)&Bs[srow][sc] = b00;
    *(short8*)&Bs[srow][sc + 8] = b01;
    *(short8*)&Bs[srow + 64][sc] = b10;
    *(short8*)&Bs[srow + 64][sc + 8] = b11;
    __syncthreads();
#pragma unroll
    for (int ks = 0; ks < 2; ks++) {
      short8 af[4], bfr[4];
#pragma unroll
      for (int i = 0; i < 4; i++) af[i] = *(const short8*)&As[wm * 64 + i * 16 + r15][ks * 32 + quad * 8];
#pragma unroll
      for (int j = 0; j < 4; j++) bfr[j] = *(const short8*)&Bs[wn * 64 + j * 16 + r15][ks * 32 + quad * 8];
#pragma unroll
      for (int i = 0; i < 4; i++)
#pragma unroll
        for (int j = 0; j < 4; j++)
          acc[i][j] = __builtin_amdgcn_mfma_f32_16x16x32_bf16(as_bf(af[i]), as_bf(bfr[j]), acc[i][j], 0, 0, 0);
    }
  }
  if (bf16out) {
    unsigned short* Cb = (unsigned short*)outp + (size_t)b * M * N;
#pragma unroll
    for (int i = 0; i < 4; i++)
#pragma unroll
      for (int j = 0; j < 4; j++)
#pragma unroll
        for (int rr = 0; rr < 4; rr++) {
          int row = m0 + wm * 64 + i * 16 + quad * 4 + rr;
          int col = n0 + wn * 64 + j * 16 + r15;
          Cb[(size_t)row * N + col] = f2bf(acc[i][j][rr]);
        }
  } else {
    float* Cb = (float*)outp + (size_t)b * M * N;
#pragma unroll
    for (int i = 0; i < 4; i++)
#pragma unroll
      for (int j = 0; j < 4; j++)
#pragma unroll
        for (int rr = 0; rr < 4; rr++) {
          int row = m0 + wm * 64 + i * 16 + quad * 4 + rr;
          int col = n0 + wn * 64 + j * 16 + r15;
          Cb[(size_t)row * N + col] = acc[i][j][rr];
        }
  }
}

// ---------------- K2: bias + l2norm q,k, v -> vT. 3 waves: seg 0=q,1=k,2=v ----------------
__global__ __launch_bounds__(192) void k_norm_qkv(const unsigned short* __restrict__ y,
                                                  const float* __restrict__ b_in,
                                                  const float* __restrict__ ss,
                                                  unsigned short* __restrict__ qn,
                                                  unsigned short* __restrict__ kn,
                                                  unsigned short* __restrict__ vT) {
  int t = threadIdx.x;
  int seg = t >> 6;
  int p = blockIdx.x * 64 + (t & 63);
  int bh = blockIdx.y;
  int b = bh >> 3, h = bh & 7;
  int obase = h * 192 + seg * 64;
  const unsigned short* yb = y + ((size_t)b * O3_ + obase) * S_ + p;
  const float* bb = b_in + obase;
  if (seg < 2) {
    float scale = (seg == 0) ? __expf(fminf(ss[h], LOGSMAX)) * LOG2E : 1.f;
    unsigned packed[32];
    float sumsq = 0.f;
#pragma unroll
    for (int d = 0; d < 64; d += 2) {
      float v0 = bf2f(yb[(size_t)d * S_]) + bb[d];
      float v1 = bf2f(yb[(size_t)(d + 1) * S_]) + bb[d + 1];
      sumsq += v0 * v0 + v1 * v1;
      packed[d >> 1] = (unsigned)f2bf(v0) | ((unsigned)f2bf(v1) << 16);
    }
    float inv = scale / fmaxf(sqrtf(sumsq), 1e-12f);
    unsigned short* dst = (seg == 0 ? qn : kn) + ((size_t)bh * S_ + p) * 64;
    unsigned outw[32];
#pragma unroll
    for (int i = 0; i < 32; i++) {
      float v0 = bf2f((unsigned short)(packed[i] & 0xffffu)) * inv;
      float v1 = bf2f((unsigned short)(packed[i] >> 16)) * inv;
      outw[i] = (unsigned)f2bf(v0) | ((unsigned)f2bf(v1) << 16);
    }
    uint4* d4 = (uint4*)dst;
#pragma unroll
    for (int i = 0; i < 8; i++)
      d4[i] = make_uint4(outw[4 * i], outw[4 * i + 1], outw[4 * i + 2], outw[4 * i + 3]);
  } else {
#pragma unroll
    for (int d = 0; d < 64; d++) {
      float v = bf2f(yb[(size_t)d * S_]) + bb[d];
      vT[((size_t)bh * DH_ + d) * S_ + p] = f2bf(v);
    }
  }
}

// ---------------- K3: attention, 32x32 MFMA, transposed-S, split-K x2, prefetch ----------------
// S^T = K Q^T; O^T = V^T P^T. Fixed-shift softmax; UNNORMALIZED partial O (bf16) + l (fp32).
__global__ __launch_bounds__(128) void k_attn(const unsigned short* __restrict__ qn,
                                              const unsigned short* __restrict__ kn,
                                              const unsigned short* __restrict__ vT,
                                              const float* __restrict__ ss,
                                              unsigned short* __restrict__ attnp,
                                              float* __restrict__ lp) {
  __shared__ __align__(16) unsigned short Ks[64][72];      // [key][d]
  __shared__ __align__(16) unsigned short Vs[64][72];      // [d][key]
  __shared__ __align__(16) unsigned short Ps[2][32][72];   // per wave [q][key]
  int t = threadIdx.x;
  int w = t >> 6;
  int lane = t & 63;
  int l31 = lane & 31, hi = lane >> 5;
  int bh = blockIdx.x;
  int q0 = blockIdx.y * 64 + w * 32;
  int split = blockIdx.z;
  int ktbase = split * 18;
  const unsigned short* qb = qn + (size_t)bh * S_ * DH_;
  const unsigned short* kb = kn + (size_t)bh * S_ * DH_;
  const unsigned short* vb = vT + (size_t)bh * DH_ * S_;
  float shift2 = __expf(fminf(ss[bh & 7], LOGSMAX)) * LOG2E;  // |s'| <= shift2

  // Q as B-fragment: n=query=l31, k(d) = ks*16 + hi*8 + j
  const unsigned short* qrow = qb + (size_t)(q0 + l31) * DH_ + hi * 8;
  short8 qf[4];
#pragma unroll
  for (int ks = 0; ks < 4; ks++) qf[ks] = *(const short8*)(qrow + ks * 16);

  const f32x16 z16 = {};
  f32x16 O0 = z16, O1 = z16;
  float l_part = 0.f;

  int row = t >> 1;          // 0..63
  int c0 = (t & 1) * 32;     // 0 or 32
  const unsigned short* kg = kb + (size_t)row * DH_ + c0;
  const unsigned short* vg = vb + (size_t)row * S_ + c0;

  // preload tile ktbase
  short8 kr[4], vr[4];
#pragma unroll
  for (int j = 0; j < 4; j++) {
    kr[j] = *(const short8*)(kg + (size_t)ktbase * 64 * DH_ + j * 8);
    vr[j] = *(const short8*)(vg + ktbase * 64 + j * 8);
  }

  for (int i = 0; i < 18; i++) {
    __syncthreads();
#pragma unroll
    for (int j = 0; j < 4; j++) {
      *(short8*)&Ks[row][c0 + j * 8] = kr[j];
      *(short8*)&Vs[row][c0 + j * 8] = vr[j];
    }
    __syncthreads();
    if (i < 17) {  // prefetch next tile; latency hides under compute below
      int kt = ktbase + i + 1;
#pragma unroll
      for (int j = 0; j < 4; j++) {
        kr[j] = *(const short8*)(kg + (size_t)kt * 64 * DH_ + j * 8);
        vr[j] = *(const short8*)(vg + kt * 64 + j * 8);
      }
    }
    // S^T = K Q^T : A = K-tile (m=key), B = Q regs (n=query)
    f32x16 sc0, sc1;
    {
      short8 a0 = *(const short8*)&Ks[l31][hi * 8];
      short8 a1 = *(const short8*)&Ks[32 + l31][hi * 8];
      sc0 = __builtin_amdgcn_mfma_f32_32x32x16_bf16(as_bf(a0), as_bf(qf[0]), z16, 0, 0, 0);
      sc1 = __builtin_amdgcn_mfma_f32_32x32x16_bf16(as_bf(a1), as_bf(qf[0]), z16, 0, 0, 0);
    }
#pragma unroll
    for (int ks = 1; ks < 4; ks++) {
      short8 a0 = *(const short8*)&Ks[l31][ks * 16 + hi * 8];
      short8 a1 = *(const short8*)&Ks[32 + l31][ks * 16 + hi * 8];
      sc0 = __builtin_amdgcn_mfma_f32_32x32x16_bf16(as_bf(a0), as_bf(qf[ks]), sc0, 0, 0, 0);
      sc1 = __builtin_amdgcn_mfma_f32_32x32x16_bf16(as_bf(a1), as_bf(qf[ks]), sc1, 0, 0, 0);
    }
    // exp2 numerator; P^T -> LDS as [q][key], 4 consecutive keys per b64 write
    float lsum = 0.f;
#pragma unroll
    for (int mt = 0; mt < 2; mt++) {
      const f32x16& s = mt ? sc1 : sc0;
#pragma unroll
      for (int g = 0; g < 4; g++) {
        float e0 = fexp2(s[g * 4 + 0] - shift2);
        float e1 = fexp2(s[g * 4 + 1] - shift2);
        float e2 = fexp2(s[g * 4 + 2] - shift2);
        float e3 = fexp2(s[g * 4 + 3] - shift2);
        lsum += (e0 + e1) + (e2 + e3);
        us4 pk = {f2bf(e0), f2bf(e1), f2bf(e2), f2bf(e3)};
        *(us4*)&Ps[w][l31][mt * 32 + g * 8 + hi * 4] = pk;
      }
    }
    l_part += lsum;
    // O^T += V^T P^T : A = V-tile (m=d), B = P (n=query) — Ps is same-wave, no barrier
#pragma unroll
    for (int ks = 0; ks < 4; ks++) {
      short8 pb = *(const short8*)&Ps[w][l31][ks * 16 + hi * 8];
      short8 va0 = *(const short8*)&Vs[l31][ks * 16 + hi * 8];
      short8 va1 = *(const short8*)&Vs[32 + l31][ks * 16 + hi * 8];
      O0 = __builtin_amdgcn_mfma_f32_32x32x16_bf16(as_bf(va0), as_bf(pb), O0, 0, 0, 0);
      O1 = __builtin_amdgcn_mfma_f32_32x32x16_bf16(as_bf(va1), as_bf(pb), O1, 0, 0, 0);
    }
  }
  float l = l_part + __shfl_xor(l_part, 32);
  if (hi == 0) lp[((size_t)(split * 16 + bh)) * S_ + q0 + l31] = l;
  unsigned short* orow = attnp + (((size_t)(split * 16 + bh)) * S_ + q0 + l31) * DH_;
#pragma unroll
  for (int mt = 0; mt < 2; mt++) {
    const f32x16& O = mt ? O1 : O0;
#pragma unroll
    for (int g = 0; g < 4; g++) {
      us4 o4 = {f2bf(O[g * 4 + 0]), f2bf(O[g * 4 + 1]), f2bf(O[g * 4 + 2]), f2bf(O[g * 4 + 3])};
      *(us4*)&orow[mt * 32 + g * 8 + hi * 4] = o4;
    }
  }
}

// ---------------- K4: depthwise 3x3 with split-combine + normalize ----------------
// attnp [split][bh][p][d] bf16 unnormalized, lp [split][bh][p] fp32 -> dwb [b][p][ch] bf16
__global__ __launch_bounds__(256) void k_dwconv(const unsigned short* __restrict__ attnp,
                                                const float* __restrict__ lp,
                                                const float* __restrict__ w_dw,
                                                unsigned short* __restrict__ dwb) {
  int t = threadIdx.x;
  int d = t & 63;
  int pj = t >> 6;
  int p = blockIdx.x * 4 + pj;
  int bh = blockIdx.y;
  int b = bh >> 3, h = bh & 7;
  int yy = p / 48, xx = p % 48;
  const unsigned short* a0 = attnp + (size_t)bh * S_ * DH_ + d;
  const unsigned short* a1 = attnp + ((size_t)(16 + bh)) * S_ * DH_ + d;
  const float* l0 = lp + (size_t)bh * S_;
  const float* l1 = lp + (size_t)(16 + bh) * S_;
  int ch = h * 64 + d;
  float w[9];
#pragma unroll
  for (int i = 0; i < 9; i++) w[i] = w_dw[ch * 9 + i];
  float acc = 0.f;
#pragma unroll
  for (int dy = -1; dy <= 1; dy++) {
    int y2 = yy + dy;
    if (y2 < 0 || y2 >= 48) continue;
#pragma unroll
    for (int dx = -1; dx <= 1; dx++) {
      int x2 = xx + dx;
      if (x2 < 0 || x2 >= 48) continue;
      int p2 = y2 * 48 + x2;  // wave-uniform
      float rl = frcp(l0[p2] + l1[p2]);
      float v = (bf2f(a0[(size_t)p2 * DH_]) + bf2f(a1[(size_t)p2 * DH_])) * rl;
      acc += v * w[(dy + 1) * 3 + dx + 1];
    }
  }
  dwb[((size_t)b * S_ + p) * INNER_ + ch] = f2bf(acc);
}

// ---------------- K6: channel LN + scales/shifts + final ----------------
__global__ __launch_bounds__(256) void k_ln_final(const float* __restrict__ pw,
                                                  const float* __restrict__ gamma,
                                                  const float* __restrict__ beta,
                                                  const float* __restrict__ x,
                                                  float* __restrict__ out) {
  __shared__ float s_sum[16][17];
  __shared__ float s_ss[16][17];
  int t = threadIdx.x;
  int pl = t & 15, cq = t >> 4;
  int gid = blockIdx.x;
  int b = gid / (S_ / 16);
  int p = (gid % (S_ / 16)) * 16 + pl;
  const float* pwb = pw + (size_t)b * INNER_ * S_;
  float sum = 0.f, sq = 0.f;
#pragma unroll
  for (int j = 0; j < 32; j++) {
    float v = pwb[(size_t)(cq * 32 + j) * S_ + p];
    sum += v;
    sq += v * v;
  }
  s_sum[cq][pl] = sum;
  s_ss[cq][pl] = sq;
  __syncthreads();
  float tot = 0.f, tss = 0.f;
#pragma unroll
  for (int i = 0; i < 16; i++) {
    tot += s_sum[i][pl];
    tss += s_ss[i][pl];
  }
  float mu = tot * (1.f / 512.f);
  float var = tss * (1.f / 512.f) - mu * mu;
  float rsig = rsqrtf(var + 1e-5f);
  const float* xb = x + (size_t)b * C_ * S_;
  float* ob = out + (size_t)b * C_ * S_;
#pragma unroll
  for (int j = 0; j < 16; j++) {
    int cc = cq * 16 + j;
    float scv = (pwb[(size_t)cc * S_ + p] - mu) * rsig * gamma[cc] + beta[cc];
    float shv = (pwb[(size_t)(cc + 256) * S_ + p] - mu) * rsig * gamma[cc + 256] + beta[cc + 256];
    ob[(size_t)cc * S_ + p] = shv + xb[(size_t)cc * S_ + p] * scv;
  }
}

extern "C" void kernel_launch(void* const* d_in, const int* in_sizes, int n_in,
                              void* d_out, int out_size, void* d_ws, size_t ws_size,
                              hipStream_t stream) {
  const float* x = (const float*)d_in[0];
  const float* w_in = (const float*)d_in[1];
  const float* b_in = (const float*)d_in[2];
  const float* ss = (const float*)d_in[3];
  const float* w_dw = (const float*)d_in[4];
  const float* w_pw = (const float*)d_in[5];
  const float* gamma = (const float*)d_in[6];
  const float* beta = (const float*)d_in[7];
  float* out = (float*)d_out;
  char* ws = (char*)d_ws;

  unsigned short* xT = (unsigned short*)(ws + 0);           // 2,359,296
  unsigned short* w_inb = (unsigned short*)(ws + 2359296);  // 786,432
  unsigned short* w_pwb = (unsigned short*)(ws + 3145728);  // 524,288
  unsigned short* qn = (unsigned short*)(ws + 3670016);     // 4,718,592
  unsigned short* kn = (unsigned short*)(ws + 8388608);     // 4,718,592
  unsigned short* vT = (unsigned short*)(ws + 13107200);    // 4,718,592
  unsigned short* dwb = (unsigned short*)(ws + 17825792);   // 4,718,592
  float* lp = (float*)(ws + 22544384);                      // 294,912  [2][16][2304] fp32
  char* big = ws + 22839296;                                // y / pw share (14,155,776)
  unsigned short* y = (unsigned short*)big;                 // bf16 [2][1536][2304] (dead after norm_qkv)
  float* pw = (float*)big;                                  // fp32 [2][512][2304] = 9,437,184
  unsigned short* attnp = (unsigned short*)(ws + 36995072); // bf16 [2][16][2304][64] = 9,437,184

  k_prep<<<2848, 256, 0, stream>>>(x, w_in, w_pw, xT, w_inb, w_pwb);
  k_gemm<<<dim3(18, 12, 2), 256, 0, stream>>>(w_inb, xT, y, O3_, S_, C_, 1);
  k_norm_qkv<<<dim3(36, 16), 192, 0, stream>>>(y, b_in, ss, qn, kn, vT);
  k_attn<<<dim3(16, 36, 2), 128, 0, stream>>>(qn, kn, vT, ss, attnp, lp);
  k_dwconv<<<dim3(576, 16), 256, 0, stream>>>(attnp, lp, w_dw, dwb);
  k_gemm<<<dim3(18, 4, 2), 256, 0, stream>>>(w_pwb, dwb, pw, INNER_, S_, INNER_, 0);
  k_ln_final<<<288, 256, 0, stream>>>(pw, gamma, beta, x, out);
}